// Round 5
// baseline (80499.658 us; speedup 1.0000x reference)
//
#include <hip/hip_runtime.h>
#include <cstdint>
#include <cstddef>

// ---- ws layout (float offsets) ----  total 294912 floats = 1.18 MB
#define O_HBUF 0                        // [3 layers][2 parity][64 rows][512] h
#define O_CBUF (3*2*64*512)             // [3 layers][64 rows][512] c state
#define WS_FLOATS (O_CBUF + 3*64*512)

__device__ __forceinline__ void gll16(const float* g, float* l) {
  __builtin_amdgcn_global_load_lds((const __attribute__((address_space(1))) void*)g,
                                   (__attribute__((address_space(3))) void*)l, 16, 0, 0);
}

// stage one [64][128] chunk: global rows (pitch 512 floats) -> LDS linear [64][128]
__device__ __forceinline__ void stage_chunk(const float* __restrict__ gsrc, float* lds,
                                            int w, int lane) {
#pragma unroll
  for (int i = 0; i < 8; ++i) {
    const int r2 = (w << 4) + (i << 1);                       // 2 rows per instr
    const float* gp = gsrc + (size_t)(r2 + (lane >> 5)) * 512 + ((lane & 31) << 2);
    gll16(gp, lds + r2 * 128);
  }
}

// One LSTM layer phase for one time-step. Block owns hidden units {2*bid, 2*bid+1}
// => gate cols col(g,u) = 512*g + 2*bid + u. Waves k-split each 128-chunk by 32.
// K layout: k<512 -> rows of Wl (input h_below), k>=512 -> rows of Ul (own h_prev).
// Accuracy: f32 4-term micro-dots accumulated in f64 (serial-chain error ~1e-7).
__device__ __forceinline__ void lstm_phase(
    int l0flag, int nch, const float* __restrict__ Wl, const float* __restrict__ Ul,
    const float* __restrict__ srcA, const float* __restrict__ srcB,
    const float* __restrict__ bias, float* __restrict__ hdst, float* __restrict__ cslab,
    const int* __restrict__ tokens, const float* __restrict__ emb,
    const float* __restrict__ W0, int t,
    float* stg, int bid, int tid)
{
  const int lane = tid & 63;
  const int w = tid >> 6;
  const int c2 = bid << 1;
  double d[8];
#pragma unroll
  for (int i = 0; i < 8; ++i) d[i] = 0.0;

  __syncthreads();                         // prior consumers of stg done
  stage_chunk(srcA, stg, w, lane);         // chunk 0

  for (int c = 0; c < nch; ++c) {
    asm volatile("s_waitcnt vmcnt(0)" ::: "memory");
    __syncthreads();
    if (c + 1 < nch) {
      const float* s2 = (c + 1 < 4) ? (srcA + (size_t)(c + 1) * 128)
                                    : (srcB + (size_t)(c + 1 - 4) * 128);
      stage_chunk(s2, stg + ((c + 1) & 1) * 8192, w, lane);
    }
    const float* buf = stg + (c & 1) * 8192;
#pragma unroll
    for (int it = 0; it < 8; ++it) {
      const int kl = (w << 5) + (it << 2);
      const int kg = (c << 7) + kl;
      const int kr = __builtin_amdgcn_readfirstlane(kg);     // wave-uniform -> SGPR
      const float* wrow = (kr < 512) ? (Wl + (size_t)kr * 2048)
                                     : (Ul + (size_t)(kr - 512) * 2048);
      const int win = kl & ~31;
      const int kb = ((kl >> 2) & 7) ^ (lane & 7);           // XOR swizzle (matches h store)
      const float4 xv = *(const float4*)&buf[lane * 128 + win + (kb << 2)];
#pragma unroll
      for (int g = 0; g < 4; ++g) {
        const int co = (g << 9) + c2;
        const float2 w0v = *(const float2*)&wrow[co];          // s_load_dwordx2 (uniform)
        const float2 w1v = *(const float2*)&wrow[2048 + co];
        const float2 w2v = *(const float2*)&wrow[4096 + co];
        const float2 w3v = *(const float2*)&wrow[6144 + co];
        const float s0 = fmaf(xv.w, w3v.x, fmaf(xv.z, w2v.x, fmaf(xv.y, w1v.x, xv.x * w0v.x)));
        const float s1 = fmaf(xv.w, w3v.y, fmaf(xv.z, w2v.y, fmaf(xv.y, w1v.y, xv.x * w0v.y)));
        d[g * 2]     += (double)s0;
        d[g * 2 + 1] += (double)s1;
      }
    }
  }

  if (l0flag && w == 0) {                  // embedding K=8 part (once, wave 0)
    const int tok = tokens[lane * 512 + t];
    const float4 e0 = *(const float4*)&emb[tok * 8];
    const float4 e1 = *(const float4*)&emb[tok * 8 + 4];
#pragma unroll
    for (int cc = 0; cc < 8; ++cc) {
      const int col = ((cc >> 1) << 9) + c2 + (cc & 1);
      float sa = e0.x * W0[col];
      sa = fmaf(e0.y, W0[1 * 2048 + col], sa);
      sa = fmaf(e0.z, W0[2 * 2048 + col], sa);
      sa = fmaf(e0.w, W0[3 * 2048 + col], sa);
      sa = fmaf(e1.x, W0[4 * 2048 + col], sa);
      sa = fmaf(e1.y, W0[5 * 2048 + col], sa);
      sa = fmaf(e1.z, W0[6 * 2048 + col], sa);
      sa = fmaf(e1.w, W0[7 * 2048 + col], sa);
      d[cc] += (double)sa;
    }
  }

  // store f64 partials: stg0 region is free (last chunk lives in stg1; all waves
  // are past stg0 reads after the final chunk's barrier)
  double* dz = (double*)stg;
#pragma unroll
  for (int i = 0; i < 8; ++i) dz[tid * 8 + i] = d[i];
  __syncthreads();

  if (tid < 128) {
    const int m_ = tid & 63, u_ = tid >> 6;
    float zf[4];
#pragma unroll
    for (int g = 0; g < 4; ++g) {
      const int cc = g * 2 + u_;
      const double zs = dz[(0 * 64 + m_) * 8 + cc] + dz[(1 * 64 + m_) * 8 + cc]
                      + dz[(2 * 64 + m_) * 8 + cc] + dz[(3 * 64 + m_) * 8 + cc]
                      + (double)bias[(g << 9) + c2 + u_];
      zf[g] = (float)zs;
    }
    const float iv = 1.f / (1.f + expf(-zf[0]));
    const float fv = 1.f / (1.f + expf(-zf[1]));
    const float gv = tanhf(zf[2]);
    const float ov = 1.f / (1.f + expf(-zf[3]));
    const int unit = c2 + u_;
    float* cp = cslab + m_ * 512 + unit;
    const float cn = fv * cp[0] + iv * gv;
    cp[0] = cn;
    const float hv = ov * tanhf(cn);
    const int win = unit & ~31;
    const int kb = ((unit >> 2) & 7) ^ (m_ & 7);
    hdst[m_ * 512 + win + (kb << 2) + (unit & 3)] = hv;    // swizzled storage
  }
}

__global__ void __launch_bounds__(256, 1)
rnn_prep(float* __restrict__ ws) {
  const int gtid = (int)blockIdx.x * 256 + (int)threadIdx.x;
  for (int i = gtid; i < WS_FLOATS; i += 65536) ws[i] = 0.f;
}

__global__ void __launch_bounds__(256, 1)
rnn_step(const int* __restrict__ tokens, const float* __restrict__ emb,
         const float* __restrict__ W0, const float* __restrict__ U0, const float* __restrict__ b0,
         const float* __restrict__ W1, const float* __restrict__ U1, const float* __restrict__ b1,
         const float* __restrict__ W2, const float* __restrict__ U2, const float* __restrict__ b2,
         const float* __restrict__ Wd, const float* __restrict__ bd,
         float* __restrict__ out, float* __restrict__ ws, int s)
{
  __shared__ __align__(16) float stg[16384];   // 64 KiB: 2x [64][128] chunk buffers
  const int tid = (int)threadIdx.x;
  const int bid = (int)blockIdx.x;
  float* hb = ws + O_HBUF;
  float* cb = ws + O_CBUF;
  const int po = (s + 1) & 1;                  // parity of prev-superstep outputs
  const int pw = s & 1;                        // parity written this superstep
  float* h0po = hb + (size_t)(0 * 2 + po) * 32768;
  float* h1po = hb + (size_t)(1 * 2 + po) * 32768;
  float* h2po = hb + (size_t)(2 * 2 + po) * 32768;
  float* h0pw = hb + (size_t)(0 * 2 + pw) * 32768;
  float* h1pw = hb + (size_t)(1 * 2 + pw) * 32768;
  float* h2pw = hb + (size_t)(2 * 2 + pw) * 32768;

  if (s < 512)                                 // L0: t=s (K=512 recurrent; +emb K=8)
    lstm_phase(1, 4, U0, U0, h0po, h0po, b0, h0pw, cb + 0 * 32768,
               tokens, emb, W0, s, stg, bid, tid);
  if (s >= 1 && s < 513)                       // L1: t=s-1
    lstm_phase(0, 8, W1, U1, h0po, h1po, b1, h1pw, cb + 1 * 32768,
               nullptr, nullptr, nullptr, 0, stg, bid, tid);
  if (s >= 2 && s < 514)                       // L2: t=s-2
    lstm_phase(0, 8, W2, U2, h1po, h2po, b2, h2pw, cb + 2 * 32768,
               nullptr, nullptr, nullptr, 0, stg, bid, tid);

  if (s >= 3 && bid < 64) {                    // FIN: logits+softmax for t=s-3 (row bid)
    const int r = bid;
    const float* h2row = h2po + (size_t)r * 512;
    float* frow = stg + 8192;
    __syncthreads();                           // prior phase fully done with stg
    if (tid < 128) {                           // unswizzle row -> linear frow
      const int j = tid;
      const int kbs = (j & ~7) | ((j & 7) ^ (r & 7));
      *(float4*)&frow[j << 2] = *(const float4*)&h2row[kbs << 2];
    }
    __syncthreads();
    const int col = tid & 127, kh = tid >> 7;
    const float* frb = frow + kh * 256;
    const float* wdb = Wd + (size_t)kh * 256 * 128 + col;
    double a = 0.0;
#pragma unroll 4
    for (int j = 0; j < 256; j += 4) {
      float sa = frb[j] * wdb[(size_t)j * 128];
      sa = fmaf(frb[j + 1], wdb[(size_t)(j + 1) * 128], sa);
      sa = fmaf(frb[j + 2], wdb[(size_t)(j + 2) * 128], sa);
      sa = fmaf(frb[j + 3], wdb[(size_t)(j + 3) * 128], sa);
      a += (double)sa;
    }
    double* dz = (double*)stg;                 // stg[0..512) floats
    dz[tid] = a;
    __syncthreads();
    float xlg = -3.0e38f;
    if (tid < 128) xlg = (float)(dz[tid] + dz[128 + tid] + (double)bd[tid]);
    float* red = stg + 512;                    // stg[512..768) floats
    red[tid] = xlg;                       __syncthreads();
    if (tid < 128) red[tid] = fmaxf(red[tid], red[tid + 128]); __syncthreads();
    if (tid < 64)  red[tid] = fmaxf(red[tid], red[tid + 64]);  __syncthreads();
    if (tid < 32)  red[tid] = fmaxf(red[tid], red[tid + 32]);  __syncthreads();
    if (tid < 16)  red[tid] = fmaxf(red[tid], red[tid + 16]);  __syncthreads();
    if (tid < 8)   red[tid] = fmaxf(red[tid], red[tid + 8]);   __syncthreads();
    if (tid < 4)   red[tid] = fmaxf(red[tid], red[tid + 4]);   __syncthreads();
    if (tid < 2)   red[tid] = fmaxf(red[tid], red[tid + 2]);   __syncthreads();
    if (tid < 1)   red[tid] = fmaxf(red[tid], red[tid + 1]);   __syncthreads();
    const float mx = red[0];              __syncthreads();
    const float ex = (tid < 128) ? expf(xlg - mx) : 0.f;
    red[tid] = ex;                        __syncthreads();
    if (tid < 128) red[tid] += red[tid + 128]; __syncthreads();
    if (tid < 64)  red[tid] += red[tid + 64];  __syncthreads();
    if (tid < 32)  red[tid] += red[tid + 32];  __syncthreads();
    if (tid < 16)  red[tid] += red[tid + 16];  __syncthreads();
    if (tid < 8)   red[tid] += red[tid + 8];   __syncthreads();
    if (tid < 4)   red[tid] += red[tid + 4];   __syncthreads();
    if (tid < 2)   red[tid] += red[tid + 2];   __syncthreads();
    if (tid < 1)   red[tid] += red[tid + 1];   __syncthreads();
    const float inv = 1.f / red[0];
    if (tid < 128) out[((size_t)r * 512 + (s - 3)) * 128 + tid] = ex * inv;
  }
}

extern "C" void kernel_launch(void* const* d_in, const int* in_sizes, int n_in,
                              void* d_out, int out_size, void* d_ws, size_t ws_size,
                              hipStream_t stream) {
  (void)in_sizes; (void)n_in; (void)out_size;
  if (ws_size < (size_t)WS_FLOATS * 4) return;   // needs 1.18 MB
  const int*   tokens = (const int*)d_in[0];
  const float* emb = (const float*)d_in[1];
  const float* W0 = (const float*)d_in[2];
  const float* U0 = (const float*)d_in[3];
  const float* b0 = (const float*)d_in[4];
  const float* W1 = (const float*)d_in[5];
  const float* U1 = (const float*)d_in[6];
  const float* b1 = (const float*)d_in[7];
  const float* W2 = (const float*)d_in[8];
  const float* U2 = (const float*)d_in[9];
  const float* b2 = (const float*)d_in[10];
  const float* Wd = (const float*)d_in[11];
  const float* bd = (const float*)d_in[12];
  float* out = (float*)d_out;
  float* ws  = (float*)d_ws;

  hipLaunchKernelGGL(rnn_prep, dim3(256), dim3(256), 0, stream, ws);
  for (int s = 0; s < 515; ++s) {
    hipLaunchKernelGGL(rnn_step, dim3(256), dim3(256), 0, stream,
                       tokens, emb, W0, U0, b0, W1, U1, b1, W2, U2, b2, Wd, bd,
                       out, ws, s);
  }
}

// Round 6
// 28899.051 us; speedup vs baseline: 2.7855x; 2.7855x over previous
//
#include <hip/hip_runtime.h>
#include <cstdint>
#include <cstddef>

#define TT 512

// ---- ws layout (float offsets) ----
#define O_HBUF 0                            // [3][2][64][512] h ping-pong
#define O_CBUF (3*2*64*512)                 // [3][64][512]    c state
#define WS_STATE (O_CBUF + 3*64*512)        // 294912 floats = 1.18 MB
#define O_CW0  WS_STATE                     // [2048 cols][512]  U0^T
#define O_CW1  (O_CW0 + 2048*512)           // [2048 cols][1024] [W1;U1]^T
#define O_CW2  (O_CW1 + 2048*1024)          // [2048 cols][1024] [W2;U2]^T
#define O_W0T  (O_CW2 + 2048*1024)          // [2048 cols][8]    W0^T
#define WS_FAST (O_W0T + 2048*8)            // 5554176 floats = 22.2 MB

__device__ __forceinline__ void gll16(const float* g, float* l) {
  __builtin_amdgcn_global_load_lds((const __attribute__((address_space(1))) void*)g,
                                   (__attribute__((address_space(3))) void*)l, 16, 0, 0);
}

// stage one [64][128] chunk: global rows (pitch 512 floats) -> LDS linear [64][128]
__device__ __forceinline__ void stage_chunk(const float* __restrict__ gsrc, float* lds,
                                            int w, int lane) {
#pragma unroll
  for (int i = 0; i < 8; ++i) {
    const int r2 = (w << 4) + (i << 1);                       // 2 rows per instr
    const float* gp = gsrc + (size_t)(r2 + (lane >> 5)) * 512 + ((lane & 31) << 2);
    gll16(gp, lds + r2 * 128);
  }
}

// One LSTM layer phase for one time-step. Block owns hidden unit u=bid
// => gate cols col(g) = 512*g + u. Waves k-split each 128-chunk by 32.
// FASTW: weights from transposed CW [col][K] via contiguous uniform s_loads.
// Accuracy: 32-term f32 fma chains per chunk, f64 accumulation across chunks.
template<bool FASTW>
__device__ __forceinline__ void lstm_phase(
    int l0flag, int nch,
    const float* __restrict__ Wl, const float* __restrict__ Ul,
    const float* __restrict__ CWsec, int Kt,
    const float* __restrict__ srcA, const float* __restrict__ srcB,
    const float* __restrict__ bias, float* __restrict__ hdst, float* __restrict__ cslab,
    const int* __restrict__ tokens, const float* __restrict__ emb,
    const float* __restrict__ W0, const float* __restrict__ W0T, int t,
    float* stg, int u, int tid)
{
  const int lane = tid & 63;
  const int w = tid >> 6;
  double d[4] = {0.0, 0.0, 0.0, 0.0};

  __syncthreads();                         // prior consumers of stg done
  stage_chunk(srcA, stg, w, lane);         // chunk 0

  for (int c = 0; c < nch; ++c) {
    asm volatile("s_waitcnt vmcnt(0)" ::: "memory");
    __syncthreads();
    if (c + 1 < nch) {
      const float* s2 = (c + 1 < 4) ? (srcA + (size_t)(c + 1) * 128)
                                    : (srcB + (size_t)(c + 1 - 4) * 128);
      stage_chunk(s2, stg + ((c + 1) & 1) * 8192, w, lane);
    }
    const float* buf = stg + (c & 1) * 8192;
    float s[4] = {0.f, 0.f, 0.f, 0.f};
#pragma unroll
    for (int it = 0; it < 8; ++it) {
      const int kl = (w << 5) + (it << 2);
      const int kg = (c << 7) + kl;
      const int kr = __builtin_amdgcn_readfirstlane(kg);     // wave-uniform -> SGPR
      const int win = kl & ~31;
      const int kb = ((kl >> 2) & 7) ^ (lane & 7);           // XOR swizzle (matches h store)
      const float4 xv = *(const float4*)&buf[lane * 128 + win + (kb << 2)];
      if constexpr (FASTW) {
#pragma unroll
        for (int g = 0; g < 4; ++g) {
          const float4 wv = *(const float4*)&CWsec[(size_t)((g << 9) + u) * Kt + kr];
          s[g] = fmaf(xv.w, wv.w, fmaf(xv.z, wv.z, fmaf(xv.y, wv.y, fmaf(xv.x, wv.x, s[g]))));
        }
      } else {
        const float* wrow = (kr < 512) ? (Wl + (size_t)kr * 2048)
                                       : (Ul + (size_t)(kr - 512) * 2048);
#pragma unroll
        for (int g = 0; g < 4; ++g) {
          const int co = (g << 9) + u;
          float sv = fmaf(xv.x, wrow[co], s[g]);
          sv = fmaf(xv.y, wrow[2048 + co], sv);
          sv = fmaf(xv.z, wrow[4096 + co], sv);
          sv = fmaf(xv.w, wrow[6144 + co], sv);
          s[g] = sv;
        }
      }
    }
#pragma unroll
    for (int g = 0; g < 4; ++g) d[g] += (double)s[g];        // per-chunk f64 flush
  }

  if (l0flag && w == 0) {                  // embedding K=8 part (once, wave 0)
    const int tok = tokens[lane * TT + t];
    const float4 e0 = *(const float4*)&emb[tok * 8];
    const float4 e1 = *(const float4*)&emb[tok * 8 + 4];
#pragma unroll
    for (int g = 0; g < 4; ++g) {
      const int col = (g << 9) + u;
      float sa;
      if constexpr (FASTW) {
        const float4 a0 = *(const float4*)&W0T[col * 8];
        const float4 a1 = *(const float4*)&W0T[col * 8 + 4];
        sa = e0.x * a0.x + e0.y * a0.y + e0.z * a0.z + e0.w * a0.w
           + e1.x * a1.x + e1.y * a1.y + e1.z * a1.z + e1.w * a1.w;
      } else {
        sa = e0.x * W0[col];
        sa = fmaf(e0.y, W0[1 * 2048 + col], sa);
        sa = fmaf(e0.z, W0[2 * 2048 + col], sa);
        sa = fmaf(e0.w, W0[3 * 2048 + col], sa);
        sa = fmaf(e1.x, W0[4 * 2048 + col], sa);
        sa = fmaf(e1.y, W0[5 * 2048 + col], sa);
        sa = fmaf(e1.z, W0[6 * 2048 + col], sa);
        sa = fmaf(e1.w, W0[7 * 2048 + col], sa);
      }
      d[g] += (double)sa;
    }
  }

  // stg0 free (last chunk lives in stg1; both nch=4 and nch=8 end on odd c)
  double* dz = (double*)stg;               // 256 threads * 4 doubles = 8 KB
#pragma unroll
  for (int g = 0; g < 4; ++g) dz[tid * 4 + g] = d[g];
  __syncthreads();

  if (tid < 64) {
    const int m = tid;
    float zf[4];
#pragma unroll
    for (int g = 0; g < 4; ++g) {
      const double zs = dz[(0 * 64 + m) * 4 + g] + dz[(1 * 64 + m) * 4 + g]
                      + dz[(2 * 64 + m) * 4 + g] + dz[(3 * 64 + m) * 4 + g]
                      + (double)bias[(g << 9) + u];
      zf[g] = (float)zs;
    }
    const float iv = 1.f / (1.f + expf(-zf[0]));
    const float fv = 1.f / (1.f + expf(-zf[1]));
    const float gv = tanhf(zf[2]);
    const float ov = 1.f / (1.f + expf(-zf[3]));
    float* cp = cslab + m * 512 + u;
    const float cn = fv * cp[0] + iv * gv;
    cp[0] = cn;
    const float hv = ov * tanhf(cn);
    const int win = u & ~31;
    const int kb = ((u >> 2) & 7) ^ (m & 7);
    hdst[m * 512 + win + (kb << 2) + (u & 3)] = hv;    // swizzled storage
  }
}

__global__ void __launch_bounds__(256)
rnn_prep(float* __restrict__ ws,
         const float* __restrict__ W0, const float* __restrict__ U0,
         const float* __restrict__ W1, const float* __restrict__ U1,
         const float* __restrict__ W2, const float* __restrict__ U2, int fastw)
{
  __shared__ float tile[64 * 65];
  const int tid = (int)threadIdx.x;
  const int bid = (int)blockIdx.x;
  const int gtid = bid * 256 + tid;
  for (int i = gtid; i < WS_STATE; i += 512 * 256) ws[i] = 0.f;
  if (!fastw) return;

  float* CW0 = ws + O_CW0;
  float* CW1 = ws + O_CW1;
  float* CW2 = ws + O_CW2;
  float* W0T = ws + O_W0T;
  if (gtid < 2048) {
#pragma unroll
    for (int e = 0; e < 8; ++e) W0T[gtid * 8 + e] = W0[(size_t)e * 2048 + gtid];
  }
  // LDS-tiled transpose: 1280 [64k x 64col] tiles over 512 blocks
  for (int tl = bid; tl < 1280; tl += 512) {
    const int kt = tl >> 5, ct = tl & 31;
    const int col0 = ct * 64;
    const float* src; float* dst; int K, k0, sk0;
    if (kt < 8)       { dst = CW0; K = 512;  k0 = kt * 64;        src = U0; sk0 = k0; }
    else if (kt < 24) { const int j = kt - 8;  dst = CW1; K = 1024; k0 = j * 64;
                        src = (j < 8) ? W1 : U1; sk0 = (j < 8) ? k0 : k0 - 512; }
    else              { const int j = kt - 24; dst = CW2; K = 1024; k0 = j * 64;
                        src = (j < 8) ? W2 : U2; sk0 = (j < 8) ? k0 : k0 - 512; }
    __syncthreads();                       // tile reusable
    const int c = tid & 63, r4 = tid >> 6;
    for (int r0 = 0; r0 < 64; r0 += 4)     // coalesced row reads
      tile[(r0 + r4) * 65 + c] = src[(size_t)(sk0 + r0 + r4) * 2048 + col0 + c];
    __syncthreads();
    const int w = tid >> 6, lane = tid & 63;
    for (int ci = w; ci < 64; ci += 4)     // coalesced col writes (64 consecutive k)
      dst[(size_t)(col0 + ci) * K + k0 + lane] = tile[lane * 65 + ci];
  }
}

template<bool FASTW>
__global__ void __launch_bounds__(256, 2)
rnn_step(const int* __restrict__ tokens, const float* __restrict__ emb,
         const float* __restrict__ W0, const float* __restrict__ U0, const float* __restrict__ b0,
         const float* __restrict__ W1, const float* __restrict__ U1, const float* __restrict__ b1,
         const float* __restrict__ W2, const float* __restrict__ U2, const float* __restrict__ b2,
         const float* __restrict__ Wd, const float* __restrict__ bd,
         float* __restrict__ out, float* __restrict__ ws, int s)
{
  __shared__ __align__(16) float stg[16384];   // 64 KiB: 2x [64][128] chunk buffers
  const int tid = (int)threadIdx.x;
  const int bid = (int)blockIdx.x;             // = hidden unit u
  float* hb = ws + O_HBUF;
  float* cb = ws + O_CBUF;
  const float* CW0 = ws + O_CW0;
  const float* CW1 = ws + O_CW1;
  const float* CW2 = ws + O_CW2;
  const float* W0T = ws + O_W0T;
  const int po = (s + 1) & 1;                  // parity of prev-superstep outputs
  const int pw = s & 1;                        // parity written this superstep
  float* h0po = hb + (size_t)(0 * 2 + po) * 32768;
  float* h1po = hb + (size_t)(1 * 2 + po) * 32768;
  float* h2po = hb + (size_t)(2 * 2 + po) * 32768;
  float* h0pw = hb + (size_t)(0 * 2 + pw) * 32768;
  float* h1pw = hb + (size_t)(1 * 2 + pw) * 32768;
  float* h2pw = hb + (size_t)(2 * 2 + pw) * 32768;

  if (s < 512)                                 // L0: t=s (K=512 recurrent + emb K=8)
    lstm_phase<FASTW>(1, 4, U0, U0, CW0, 512, h0po, h0po, b0, h0pw, cb + 0 * 32768,
                      tokens, emb, W0, W0T, s, stg, bid, tid);
  if (s >= 1 && s < 513)                       // L1: t=s-1
    lstm_phase<FASTW>(0, 8, W1, U1, CW1, 1024, h0po, h1po, b1, h1pw, cb + 1 * 32768,
                      nullptr, nullptr, nullptr, nullptr, 0, stg, bid, tid);
  if (s >= 2 && s < 514)                       // L2: t=s-2
    lstm_phase<FASTW>(0, 8, W2, U2, CW2, 1024, h1po, h2po, b2, h2pw, cb + 2 * 32768,
                      nullptr, nullptr, nullptr, nullptr, 0, stg, bid, tid);

  if (s >= 3 && bid < 64) {                    // FIN: logits+softmax for t=s-3 (row bid)
    const int r = bid;
    const float* h2row = h2po + (size_t)r * 512;
    float* frow = stg + 8192;
    __syncthreads();                           // prior phase fully done with stg
    if (tid < 128) {                           // unswizzle row -> linear frow
      const int j = tid;
      const int kbs = (j & ~7) | ((j & 7) ^ (r & 7));
      *(float4*)&frow[j << 2] = *(const float4*)&h2row[kbs << 2];
    }
    __syncthreads();
    const int col = tid & 127, kh = tid >> 7;
    const float* frb = frow + kh * 256;
    const float* wdb = Wd + (size_t)kh * 256 * 128 + col;
    double a = 0.0;
#pragma unroll 4
    for (int j = 0; j < 256; j += 4) {
      float sa = frb[j] * wdb[(size_t)j * 128];
      sa = fmaf(frb[j + 1], wdb[(size_t)(j + 1) * 128], sa);
      sa = fmaf(frb[j + 2], wdb[(size_t)(j + 2) * 128], sa);
      sa = fmaf(frb[j + 3], wdb[(size_t)(j + 3) * 128], sa);
      a += (double)sa;
    }
    double* dz = (double*)stg;                 // floats [0,512)
    dz[tid] = a;
    __syncthreads();
    float xlg = -3.0e38f;
    if (tid < 128) xlg = (float)(dz[tid] + dz[128 + tid] + (double)bd[tid]);
    float* red = stg + 512;                    // floats [512,768)
    red[tid] = xlg;                       __syncthreads();
    if (tid < 128) red[tid] = fmaxf(red[tid], red[tid + 128]); __syncthreads();
    if (tid < 64)  red[tid] = fmaxf(red[tid], red[tid + 64]);  __syncthreads();
    if (tid < 32)  red[tid] = fmaxf(red[tid], red[tid + 32]);  __syncthreads();
    if (tid < 16)  red[tid] = fmaxf(red[tid], red[tid + 16]);  __syncthreads();
    if (tid < 8)   red[tid] = fmaxf(red[tid], red[tid + 8]);   __syncthreads();
    if (tid < 4)   red[tid] = fmaxf(red[tid], red[tid + 4]);   __syncthreads();
    if (tid < 2)   red[tid] = fmaxf(red[tid], red[tid + 2]);   __syncthreads();
    if (tid < 1)   red[tid] = fmaxf(red[tid], red[tid + 1]);   __syncthreads();
    const float mx = red[0];              __syncthreads();
    const float ex = (tid < 128) ? expf(xlg - mx) : 0.f;
    red[tid] = ex;                        __syncthreads();
    if (tid < 128) red[tid] += red[tid + 128]; __syncthreads();
    if (tid < 64)  red[tid] += red[tid + 64];  __syncthreads();
    if (tid < 32)  red[tid] += red[tid + 32];  __syncthreads();
    if (tid < 16)  red[tid] += red[tid + 16];  __syncthreads();
    if (tid < 8)   red[tid] += red[tid + 8];   __syncthreads();
    if (tid < 4)   red[tid] += red[tid + 4];   __syncthreads();
    if (tid < 2)   red[tid] += red[tid + 2];   __syncthreads();
    if (tid < 1)   red[tid] += red[tid + 1];   __syncthreads();
    const float inv = 1.f / red[0];
    if (tid < 128) out[((size_t)r * 512 + (s - 3)) * 128 + tid] = ex * inv;
  }
}

extern "C" void kernel_launch(void* const* d_in, const int* in_sizes, int n_in,
                              void* d_out, int out_size, void* d_ws, size_t ws_size,
                              hipStream_t stream) {
  (void)in_sizes; (void)n_in; (void)out_size;
  if (ws_size < (size_t)WS_STATE * 4) return;
  const bool fastw = ws_size >= (size_t)WS_FAST * 4;
  const int*   tokens = (const int*)d_in[0];
  const float* emb = (const float*)d_in[1];
  const float* W0 = (const float*)d_in[2];
  const float* U0 = (const float*)d_in[3];
  const float* b0 = (const float*)d_in[4];
  const float* W1 = (const float*)d_in[5];
  const float* U1 = (const float*)d_in[6];
  const float* b1 = (const float*)d_in[7];
  const float* W2 = (const float*)d_in[8];
  const float* U2 = (const float*)d_in[9];
  const float* b2 = (const float*)d_in[10];
  const float* Wd = (const float*)d_in[11];
  const float* bd = (const float*)d_in[12];
  float* out = (float*)d_out;
  float* ws  = (float*)d_ws;

  hipLaunchKernelGGL(rnn_prep, dim3(512), dim3(256), 0, stream,
                     ws, W0, U0, W1, U1, W2, U2, fastw ? 1 : 0);
  for (int s = 0; s < 515; ++s) {
    if (fastw)
      hipLaunchKernelGGL((rnn_step<true>), dim3(512), dim3(256), 0, stream,
                         tokens, emb, W0, U0, b0, W1, U1, b1, W2, U2, b2, Wd, bd,
                         out, ws, s);
    else
      hipLaunchKernelGGL((rnn_step<false>), dim3(512), dim3(256), 0, stream,
                         tokens, emb, W0, U0, b0, W1, U1, b1, W2, U2, b2, Wd, bd,
                         out, ws, s);
  }
}